// Round 5
// baseline (154.492 us; speedup 1.0000x reference)
//
#include <hip/hip_runtime.h>

#define TB 2
#define TN 4096
#define TH 4
#define THID 128
#define TOUT 64
#define NW 128   // N/32 bitmask words per row

using f4    = __attribute__((ext_vector_type(4))) float;
using s16x8 = __attribute__((ext_vector_type(8))) short;
using s16x4 = __attribute__((ext_vector_type(4))) short;
using u32x4 = __attribute__((ext_vector_type(4))) unsigned;

static __device__ __forceinline__ short f2bf(float f){
  unsigned u = __float_as_uint(f);
  unsigned r = u + 0x7FFFu + ((u >> 16) & 1u);
  return (short)(r >> 16);
}
static __device__ __forceinline__ float bf2f(short s){
  return __uint_as_float(((unsigned)(unsigned short)s) << 16);
}
static __device__ __forceinline__ unsigned encf(float f){
  unsigned u = __float_as_uint(f);
  return (u & 0x80000000u) ? ~u : (u | 0x80000000u);
}
static __device__ __forceinline__ float decf(unsigned u){
  unsigned v = (u & 0x80000000u) ? (u & 0x7FFFFFFFu) : ~u;
  return __uint_as_float(v);
}
static __device__ __forceinline__ void gll16(const void* g, void* l){
  __builtin_amdgcn_global_load_lds((const __attribute__((address_space(1))) unsigned int*)g,
                                   (__attribute__((address_space(3))) unsigned int*)l, 16, 0, 0);
}
static __device__ __forceinline__ f4 mfma_bf16(s16x8 a, s16x8 b, f4 c){
  return __builtin_amdgcn_mfma_f32_16x16x32_bf16(a, b, c, 0, 0, 0);
}

// ---------------- pack adjacency to bits (+ clear mx) ----------------
__global__ void k_pack(const int* __restrict__ adj, unsigned* __restrict__ adjp,
                       unsigned* __restrict__ mx){
  if (blockIdx.x == 0 && threadIdx.x < 16) mx[threadIdx.x] = 0;
  int t = blockIdx.x * 256 + threadIdx.x;            // word index, 1,048,576 total
  const int4* p = (const int4*)adj + (size_t)t * 8;  // 32 ints
  unsigned m = 0;
#pragma unroll
  for (int i = 0; i < 8; ++i){
    int4 v = p[i];
    m |= (v.x != 0 ? 1u : 0u) << (i*4+0);
    m |= (v.y != 0 ? 1u : 0u) << (i*4+1);
    m |= (v.z != 0 ? 1u : 0u) << (i*4+2);
    m |= (v.w != 0 ? 1u : 0u) << (i*4+3);
  }
  adjp[t] = m;
}

// ---------------- f32 -> bf16 hi/lo split (x, W_heads) ----------------
__global__ void k_split(const float* __restrict__ x, short* __restrict__ hi, short* __restrict__ lo){
  int t = blockIdx.x * 256 + threadIdx.x;
  f4 v = ((const f4*)x)[t];
  s16x4 h, l;
#pragma unroll
  for (int e = 0; e < 4; ++e){
    short hb = f2bf(v[e]);
    h[e] = hb;
    l[e] = f2bf(v[e] - bf2f(hb));
  }
  ((s16x4*)hi)[t] = h;
  ((s16x4*)lo)[t] = l;
}
// ---------------- f32 -> bf16 (W_out) ----------------
__global__ void k_cvt(const float* __restrict__ x, short* __restrict__ o){
  int t = blockIdx.x * 256 + threadIdx.x;
  f4 v = ((const f4*)x)[t];
  s16x4 h;
#pragma unroll
  for (int e = 0; e < 4; ++e) h[e] = f2bf(v[e]);
  ((s16x4*)o)[t] = h;
}

// ---------------- layer-1 projection + f1/f2/exp epilogue (split bf16, ~f32 acc) ----------------
// grid 256 = (nblk 4)*(mblk 64), 512 thr. C rows = n_out(512), cols = m(8192).
__global__ __launch_bounds__(512, 2) void k_gemm1(
    const short* __restrict__ xh, const short* __restrict__ xl,
    const short* __restrict__ wh, const short* __restrict__ wl,
    const float* __restrict__ a1h, const float* __restrict__ a2h,
    short* __restrict__ hTb, float* __restrict__ f1g,
    float* __restrict__ Qa, float* __restrict__ Sa, unsigned* __restrict__ mx){
  __shared__ short tiles[2][4][8192];  // dbuf x {Ah, Al (W), Bh, Bl (x)}: [128][64] swizzled
  __shared__ float red[2][128][2];
  __shared__ float bmx[2];
  int tid = threadIdx.x, lane = tid & 63, w = tid >> 6;
  int kgrp = lane >> 4, li = lane & 15;
  int nblk = blockIdx.x >> 6, mblk = blockIdx.x & 63;
  int n0 = nblk * 128, m0 = mblk * 128;
  int wn = w >> 2, wm = w & 3;
  const f4 fz = {0.f, 0.f, 0.f, 0.f};
  f4 acc[4][2];
#pragma unroll
  for (int i = 0; i < 4; ++i)
#pragma unroll
    for (int j = 0; j < 2; ++j) acc[i][j] = fz;

  // prologue: stage kt=0
#pragma unroll
  for (int tno = 0; tno < 4; ++tno){
    const short* gb = (tno==0 ? wh : tno==1 ? wl : tno==2 ? xh : xl);
    int r0 = (tno < 2) ? n0 : m0;
#pragma unroll
    for (int i = 0; i < 2; ++i){
      int s = (i*8 + w)*64 + lane;
      int row = s >> 3, c = s & 7, cs = c ^ (row & 7);
      gll16(gb + (size_t)(r0 + row)*512 + cs*8, (char*)tiles[0][tno] + (i*8+w)*1024);
    }
  }
  asm volatile("s_waitcnt vmcnt(0)" ::: "memory");
  __syncthreads();

  for (int kt = 0; kt < 8; ++kt){
    int cur = kt & 1;
    if (kt < 7){
      int k0 = (kt+1) * 64;
#pragma unroll
      for (int tno = 0; tno < 4; ++tno){
        const short* gb = (tno==0 ? wh : tno==1 ? wl : tno==2 ? xh : xl);
        int r0 = (tno < 2) ? n0 : m0;
#pragma unroll
        for (int i = 0; i < 2; ++i){
          int s = (i*8 + w)*64 + lane;
          int row = s >> 3, c = s & 7, cs = c ^ (row & 7);
          gll16(gb + (size_t)(r0 + row)*512 + k0 + cs*8, (char*)tiles[cur^1][tno] + (i*8+w)*1024);
        }
      }
    }
    const char* t0 = (const char*)tiles[cur][0];
    const char* t1 = (const char*)tiles[cur][1];
    const char* t2 = (const char*)tiles[cur][2];
    const char* t3 = (const char*)tiles[cur][3];
#pragma unroll
    for (int ks = 0; ks < 2; ++ks){
      int ck = ks*4 + kgrp;
      s16x8 ah[4], al[4], bh[2], bl[2];
#pragma unroll
      for (int fn = 0; fn < 4; ++fn){
        int row = wn*64 + fn*16 + li;
        int off = row*128 + ((ck ^ (row & 7)) << 4);
        ah[fn] = *(const s16x8*)(t0 + off);
        al[fn] = *(const s16x8*)(t1 + off);
      }
#pragma unroll
      for (int fm = 0; fm < 2; ++fm){
        int row = wm*32 + fm*16 + li;
        int off = row*128 + ((ck ^ (row & 7)) << 4);
        bh[fm] = *(const s16x8*)(t2 + off);
        bl[fm] = *(const s16x8*)(t3 + off);
      }
#pragma unroll
      for (int fn = 0; fn < 4; ++fn)
#pragma unroll
        for (int fm = 0; fm < 2; ++fm)
          acc[fn][fm] = mfma_bf16(ah[fn], bh[fm], acc[fn][fm]);
#pragma unroll
      for (int fn = 0; fn < 4; ++fn)
#pragma unroll
        for (int fm = 0; fm < 2; ++fm)
          acc[fn][fm] = mfma_bf16(ah[fn], bl[fm], acc[fn][fm]);
#pragma unroll
      for (int fn = 0; fn < 4; ++fn)
#pragma unroll
        for (int fm = 0; fm < 2; ++fm)
          acc[fn][fm] = mfma_bf16(al[fn], bh[fm], acc[fn][fm]);
    }
    asm volatile("s_waitcnt vmcnt(0)" ::: "memory");
    __syncthreads();
  }
  int head = nblk;
  // C write (bf16 hT)
#pragma unroll
  for (int fn = 0; fn < 4; ++fn){
#pragma unroll
    for (int fm = 0; fm < 2; ++fm){
#pragma unroll
      for (int r = 0; r < 4; ++r){
        int nout = n0 + wn*64 + fn*16 + kgrp*4 + r;
        int m = m0 + wm*32 + fm*16 + li;
        int b = m >> 12, n = m & 4095;
        int hid = nout & 127;
        size_t idx = ((size_t)((b*TH + head)*THID + hid))*TN + n;
        hTb[idx] = f2bf(acc[fn][fm][r]);
      }
    }
  }
  // fold f1 = h.a1, f2 = h.a2 from f32 acc (rows spread over wn,fn,kgrp,r)
  const float* a1p = a1h + head*THID;
  const float* a2p = a2h + head*THID;
  float s1[2] = {0.f, 0.f}, s2[2] = {0.f, 0.f};
#pragma unroll
  for (int fn = 0; fn < 4; ++fn)
#pragma unroll
    for (int r = 0; r < 4; ++r){
      int row = wn*64 + fn*16 + kgrp*4 + r;
      float w1 = a1p[row], w2 = a2p[row];
#pragma unroll
      for (int fm = 0; fm < 2; ++fm){
        s1[fm] = fmaf(acc[fn][fm][r], w1, s1[fm]);
        s2[fm] = fmaf(acc[fn][fm][r], w2, s2[fm]);
      }
    }
#pragma unroll
  for (int fm = 0; fm < 2; ++fm){
    s1[fm] += __shfl_xor(s1[fm], 16); s1[fm] += __shfl_xor(s1[fm], 32);
    s2[fm] += __shfl_xor(s2[fm], 16); s2[fm] += __shfl_xor(s2[fm], 32);
  }
  if (kgrp == 0){
#pragma unroll
    for (int fm = 0; fm < 2; ++fm){
      int col = wm*32 + fm*16 + li;
      red[wn][col][0] = s1[fm];
      red[wn][col][1] = s2[fm];
    }
  }
  __syncthreads();
  if (tid < 128){
    float f1v = red[0][tid][0] + red[1][tid][0];
    float f2v = red[0][tid][1] + red[1][tid][1];
    int m = m0 + tid, b = m >> 12, n = m & 4095;
    int idx = (b*TH + head)*TN + n;
    f1g[idx] = f1v;
    Qa[idx] = expf(f2v);
    Sa[idx] = expf(0.2f*f2v);
    float wmx = f2v;
#pragma unroll
    for (int d = 1; d < 64; d <<= 1) wmx = fmaxf(wmx, __shfl_xor(wmx, d));
    if ((tid & 63) == 0) bmx[tid >> 6] = wmx;
  }
  __syncthreads();
  if (tid == 0){
    int b = m0 >> 12;
    atomicMax(&mx[b*TH + head], encf(fmaxf(bmx[0], bmx[1])));
  }
}

// ---------------- layer-1 fused attention: partial h' = att @ h ----------------
// grid 1024 = (js 4)*(b 2)*(h 4)*(rblk 32); 4 waves x 32 rows x 128 cols, dbuf, 4 blk/CU
__global__ __launch_bounds__(256, 4) void k_attn1(
    const short* __restrict__ hTb, const float* __restrict__ f1,
    const float* __restrict__ Qa, const float* __restrict__ Sa,
    const unsigned* __restrict__ adjp, const unsigned* __restrict__ mx,
    short* __restrict__ part, float* __restrict__ sums){
  __shared__ short tile[2][8192];      // [128 hid][64 j] swizzled, dbuf (32 KB)
  __shared__ float Qs[1024], Ss[1024]; // 8 KB
  int tid = threadIdx.x, lane = tid & 63, w = tid >> 6;   // w in 0..3
  int kgrp = lane >> 4, li = lane & 15;
  int bid = blockIdx.x;
  int js = bid >> 8, b = (bid >> 7) & 1, h = (bid >> 5) & 3, rblk = bid & 31;
  int bh = b*TH + h;
  int jbase = js * 1024;
  const short* hbase = hTb + ((size_t)bh*THID)*TN;

  // stage Q/S (4KB each) + tile 0
  gll16(Qa + (size_t)bh*TN + jbase + w*256 + lane*4, (char*)Qs + w*1024);
  gll16(Sa + (size_t)bh*TN + jbase + w*256 + lane*4, (char*)Ss + w*1024);
#pragma unroll
  for (int i = 0; i < 4; ++i){
    int s = (i*4 + w)*64 + lane;
    int row = s >> 3, c = s & 7, cs = c ^ (row & 7);
    gll16(hbase + (size_t)row*TN + jbase + cs*8, (char*)tile[0] + (i*4+w)*1024);
  }
  int r0 = rblk*128 + w*32;
  float Pv[2], Rv[2];
  int rowa[2];
  float mf = decf(mx[bh]);
#pragma unroll
  for (int rf = 0; rf < 2; ++rf){
    int row = r0 + rf*16 + li;
    rowa[rf] = row;
    float f1v = f1[bh*TN + row];
    float e = f1v + mf;
    float m = e > 0.f ? e : 0.2f*e;       // leaky upper bound of all scores in row
    Pv[rf] = expf(f1v - m);
    Rv[rf] = expf(0.2f*f1v - m);
  }
  const f4 fz = {0.f,0.f,0.f,0.f};
  f4 acc[2][8];
#pragma unroll
  for (int i = 0; i < 2; ++i)
#pragma unroll
    for (int j = 0; j < 8; ++j) acc[i][j] = fz;
  f4 accs[2] = {fz, fz};
  s16x8 ones;
#pragma unroll
  for (int e = 0; e < 8; ++e) ones[e] = (short)0x3F80;

  // adjacency prefetch for jt=0 (register dbuf)
  uint2 awc[2], awn[2];
#pragma unroll
  for (int rf = 0; rf < 2; ++rf)
    awc[rf] = *(const uint2*)&adjp[(size_t)(b*TN + rowa[rf])*NW + (jbase >> 5)];

  asm volatile("s_waitcnt vmcnt(0)" ::: "memory");
  __syncthreads();

  for (int jt = 0; jt < 16; ++jt){
    int cur = jt & 1;
    if (jt < 15){
      int jg = jbase + (jt+1)*64;
#pragma unroll
      for (int i = 0; i < 4; ++i){
        int s = (i*4 + w)*64 + lane;
        int row = s >> 3, c = s & 7, cs = c ^ (row & 7);
        gll16(hbase + (size_t)row*TN + jg + cs*8, (char*)tile[cur^1] + (i*4+w)*1024);
      }
    }
    int jn = jt < 15 ? jt+1 : jt;
#pragma unroll
    for (int rf = 0; rf < 2; ++rf)
      awn[rf] = *(const uint2*)&adjp[(size_t)(b*TN + rowa[rf])*NW + ((jbase + jn*64) >> 5)];
    int j0 = jt*64;
    const char* tp = (const char*)tile[cur];
#pragma unroll
    for (int ks = 0; ks < 2; ++ks){
      int jloc = j0 + ks*32 + kgrp*8;
      float qv[8], sv[8];
      *(f4*)&qv[0] = *(const f4*)&Qs[jloc];
      *(f4*)&qv[4] = *(const f4*)&Qs[jloc+4];
      *(f4*)&sv[0] = *(const f4*)&Ss[jloc];
      *(f4*)&sv[4] = *(const f4*)&Ss[jloc+4];
      s16x8 af[2];
#pragma unroll
      for (int rf = 0; rf < 2; ++rf){
        unsigned word = ks ? awc[rf].y : awc[rf].x;
        unsigned byt = (word >> (kgrp*8)) & 0xFFu;
        float P = Pv[rf], R = Rv[rf];
        u32x4 pw;
#pragma unroll
        for (int pe = 0; pe < 4; ++pe){
          float va = fmaxf(P*qv[2*pe],   R*sv[2*pe]);
          float vb = fmaxf(P*qv[2*pe+1], R*sv[2*pe+1]);
          va = (byt & (1u << (2*pe)))   ? va : 0.f;
          vb = (byt & (1u << (2*pe+1))) ? vb : 0.f;
          unsigned ua = __float_as_uint(va) + 0x8000u;  // round-half-up to bf16
          unsigned ub = __float_as_uint(vb) + 0x8000u;
          pw[pe] = __builtin_amdgcn_perm(ub, ua, 0x07060302); // pack hi16s
        }
        af[rf] = __builtin_bit_cast(s16x8, pw);
      }
      accs[0] = mfma_bf16(af[0], ones, accs[0]);  // row sums via MFMA
      accs[1] = mfma_bf16(af[1], ones, accs[1]);
#pragma unroll
      for (int cf = 0; cf < 8; ++cf){
        int col = cf*16 + li;
        int off = col*128 + (((ks*4 + kgrp) ^ (col & 7)) << 4);
        s16x8 bfr = *(const s16x8*)(tp + off);
        acc[0][cf] = mfma_bf16(af[0], bfr, acc[0][cf]);
        acc[1][cf] = mfma_bf16(af[1], bfr, acc[1][cf]);
      }
    }
    asm volatile("s_waitcnt vmcnt(0)" ::: "memory");
    __syncthreads();
    awc[0] = awn[0]; awc[1] = awn[1];
  }
  int sl = js*8 + bh;
  if (li == 0){
#pragma unroll
    for (int rf = 0; rf < 2; ++rf)
#pragma unroll
      for (int r = 0; r < 4; ++r)
        sums[(size_t)sl*TN + r0 + rf*16 + kgrp*4 + r] = accs[rf][r];
  }
#pragma unroll
  for (int rf = 0; rf < 2; ++rf)
#pragma unroll
    for (int cf = 0; cf < 8; ++cf)
#pragma unroll
      for (int r = 0; r < 4; ++r){
        int row = r0 + rf*16 + kgrp*4 + r;
        int hid = cf*16 + li;
        part[((size_t)sl*TN + row)*THID + hid] = f2bf(acc[rf][cf][r]);
      }
}

// ---------------- combine layer-1 partials (bf16, 4 slices) -> x_cat (ELU, bf16) ----------------
__global__ void k_comb1(const short* __restrict__ part, const float* __restrict__ sums,
                        short* __restrict__ xcat){
  int t = blockIdx.x*256 + threadIdx.x;   // 524,288
  int hid8 = t & 15, n = (t >> 4) & 4095, h = (t >> 16) & 3, b = t >> 18;
  int bh = b*TH + h;
  float a[8] = {0,0,0,0,0,0,0,0};
  float s = 0.f;
#pragma unroll
  for (int js = 0; js < 4; ++js){
    size_t rowoff = (size_t)(js*8 + bh)*TN + n;
    s16x8 pv = *(const s16x8*)(part + rowoff*THID + hid8*8);
#pragma unroll
    for (int e = 0; e < 8; ++e) a[e] += bf2f(pv[e]);
    s += sums[rowoff];
  }
  float inv = 1.f / s;
  s16x8 o;
#pragma unroll
  for (int e = 0; e < 8; ++e){
    float x = a[e] * inv;
    o[e] = f2bf(x > 0.f ? x : expm1f(x));
  }
  *(s16x8*)(xcat + ((size_t)(b*TN + n))*512 + h*128 + hid8*8) = o;
}

// ---------------- layer-2 projection + f1o/f2o ----------------
// grid 256, 128 thr (2 waves x 16 rows), cols = 64
__global__ __launch_bounds__(128) void k_gemm2(
    const short* __restrict__ xcat, const short* __restrict__ wo,
    const float* __restrict__ a1o, const float* __restrict__ a2o,
    short* __restrict__ h2T, float* __restrict__ f1o,
    float* __restrict__ Q2, float* __restrict__ S2, unsigned* __restrict__ mx2){
  int tid = threadIdx.x, lane = tid & 63, w = tid >> 6;
  int kgrp = lane >> 4, li = lane & 15;
  int m0 = blockIdx.x * 32;
  const f4 fz = {0.f,0.f,0.f,0.f};
  f4 acc[4] = {fz, fz, fz, fz};
  int rowA = m0 + w*16 + li;
  for (int kt = 0; kt < 16; ++kt){
    int k = kt*32 + kgrp*8;
    s16x8 a = *(const s16x8*)(xcat + (size_t)rowA*512 + k);
#pragma unroll
    for (int cf = 0; cf < 4; ++cf){
      int col = cf*16 + li;
      s16x8 bfr = *(const s16x8*)(wo + (size_t)col*512 + k);
      acc[cf] = mfma_bf16(a, bfr, acc[cf]);
    }
  }
  float p1[4] = {0,0,0,0}, p2[4] = {0,0,0,0};
#pragma unroll
  for (int cf = 0; cf < 4; ++cf){
    int o = cf*16 + li;
    float w1 = a1o[o], w2 = a2o[o];
#pragma unroll
    for (int r = 0; r < 4; ++r){
      p1[r] = fmaf(acc[cf][r], w1, p1[r]);
      p2[r] = fmaf(acc[cf][r], w2, p2[r]);
    }
  }
#pragma unroll
  for (int r = 0; r < 4; ++r){
#pragma unroll
    for (int d = 1; d < 16; d <<= 1){
      p1[r] += __shfl_xor(p1[r], d);
      p2[r] += __shfl_xor(p2[r], d);
    }
  }
#pragma unroll
  for (int cf = 0; cf < 4; ++cf)
#pragma unroll
    for (int r = 0; r < 4; ++r){
      int row = m0 + w*16 + kgrp*4 + r;
      int o = cf*16 + li;
      int b = row >> 12, n = row & 4095;
      h2T[((size_t)(b*TOUT + o))*TN + n] = f2bf(acc[cf][r]);
    }
  if (li == 0){
#pragma unroll
    for (int r = 0; r < 4; ++r){
      int row = m0 + w*16 + kgrp*4 + r;   // row == b*N + n
      f1o[row] = p1[r];
      Q2[row] = expf(p2[r]);
      S2[row] = expf(0.2f*p2[r]);
    }
  }
  // block-level max reduce -> ONE atomic per block
  float m2 = fmaxf(fmaxf(p2[0], p2[1]), fmaxf(p2[2], p2[3]));
  m2 = fmaxf(m2, __shfl_xor(m2, 16));
  m2 = fmaxf(m2, __shfl_xor(m2, 32));
  __shared__ float bm[2];
  if (lane == 0) bm[w] = m2;
  __syncthreads();
  if (tid == 0) atomicMax(&mx2[m0 >> 12], encf(fmaxf(bm[0], bm[1])));
}

// ---------------- layer-2 fused attention (partials) ----------------
// grid 1024 = (js 8)*(b 2)*(rblk 64); 4 waves x 16 rows x 64 cols, dbuf, 4 blk/CU
__global__ __launch_bounds__(256, 4) void k_attn2(
    const short* __restrict__ h2T, const float* __restrict__ f1o,
    const float* __restrict__ Q2, const float* __restrict__ S2,
    const unsigned* __restrict__ adjp, const unsigned* __restrict__ mx2,
    float* __restrict__ part, float* __restrict__ sums){
  __shared__ short tile[2][4096];    // [64 o][64 j] swizzled, dbuf (16 KB)
  __shared__ float Qs[512], Ss[512]; // 4 KB
  int tid = threadIdx.x, lane = tid & 63, w = tid >> 6;  // w in 0..3
  int kgrp = lane >> 4, li = lane & 15;
  int bid = blockIdx.x;
  int js = bid >> 7, b = (bid >> 6) & 1, rblk = bid & 63;
  int jbase = js * 512;
  const short* hbase = h2T + (size_t)b*TOUT*TN;

  if (w < 2) gll16(Q2 + (size_t)b*TN + jbase + w*256 + lane*4, (char*)Qs + w*1024);
  else       gll16(S2 + (size_t)b*TN + jbase + (w-2)*256 + lane*4, (char*)Ss + (w-2)*1024);
#pragma unroll
  for (int i = 0; i < 2; ++i){
    int s = (i*4 + w)*64 + lane;
    int row = s >> 3, c = s & 7, cs = c ^ (row & 7);
    gll16(hbase + (size_t)row*TN + jbase + cs*8, (char*)tile[0] + (i*4+w)*1024);
  }
  int r0 = rblk*64 + w*16;
  int rowa = r0 + li;
  float mf = decf(mx2[b]);
  float f1v = f1o[b*TN + rowa];
  float e0 = f1v + mf;
  float m0v = e0 > 0.f ? e0 : 0.2f*e0;
  float Pv = expf(f1v - m0v);
  float Rv = expf(0.2f*f1v - m0v);
  const f4 fz = {0.f,0.f,0.f,0.f};
  f4 acc[4] = {fz, fz, fz, fz};
  f4 accs = fz;
  s16x8 ones;
#pragma unroll
  for (int e = 0; e < 8; ++e) ones[e] = (short)0x3F80;

  uint2 awc, awn;
  awc = *(const uint2*)&adjp[(size_t)(b*TN + rowa)*NW + (jbase >> 5)];

  asm volatile("s_waitcnt vmcnt(0)" ::: "memory");
  __syncthreads();

  for (int jt = 0; jt < 8; ++jt){
    int cur = jt & 1;
    if (jt < 7){
      int jg = jbase + (jt+1)*64;
#pragma unroll
      for (int i = 0; i < 2; ++i){
        int s = (i*4 + w)*64 + lane;
        int row = s >> 3, c = s & 7, cs = c ^ (row & 7);
        gll16(hbase + (size_t)row*TN + jg + cs*8, (char*)tile[cur^1] + (i*4+w)*1024);
      }
    }
    int jn = jt < 7 ? jt+1 : jt;
    awn = *(const uint2*)&adjp[(size_t)(b*TN + rowa)*NW + ((jbase + jn*64) >> 5)];
    int j0 = jt*64;
    const char* tp = (const char*)tile[cur];
#pragma unroll
    for (int ks = 0; ks < 2; ++ks){
      int jloc = j0 + ks*32 + kgrp*8;
      float qv[8], sv[8];
      *(f4*)&qv[0] = *(const f4*)&Qs[jloc];
      *(f4*)&qv[4] = *(const f4*)&Qs[jloc+4];
      *(f4*)&sv[0] = *(const f4*)&Ss[jloc];
      *(f4*)&sv[4] = *(const f4*)&Ss[jloc+4];
      unsigned word = ks ? awc.y : awc.x;
      unsigned byt = (word >> (kgrp*8)) & 0xFFu;
      u32x4 pw;
#pragma unroll
      for (int pe = 0; pe < 4; ++pe){
        float va = fmaxf(Pv*qv[2*pe],   Rv*sv[2*pe]);
        float vb = fmaxf(Pv*qv[2*pe+1], Rv*sv[2*pe+1]);
        va = (byt & (1u << (2*pe)))   ? va : 0.f;
        vb = (byt & (1u << (2*pe+1))) ? vb : 0.f;
        unsigned ua = __float_as_uint(va) + 0x8000u;
        unsigned ub = __float_as_uint(vb) + 0x8000u;
        pw[pe] = __builtin_amdgcn_perm(ub, ua, 0x07060302);
      }
      s16x8 af = __builtin_bit_cast(s16x8, pw);
      accs = mfma_bf16(af, ones, accs);
#pragma unroll
      for (int cf = 0; cf < 4; ++cf){
        int col = cf*16 + li;
        int off = col*128 + (((ks*4 + kgrp) ^ (col & 7)) << 4);
        s16x8 bfr = *(const s16x8*)(tp + off);
        acc[cf] = mfma_bf16(af, bfr, acc[cf]);
      }
    }
    asm volatile("s_waitcnt vmcnt(0)" ::: "memory");
    __syncthreads();
    awc = awn;
  }
  int sl = js*2 + b;
  if (li == 0){
#pragma unroll
    for (int r = 0; r < 4; ++r)
      sums[(size_t)sl*TN + r0 + kgrp*4 + r] = accs[r];
  }
#pragma unroll
  for (int cf = 0; cf < 4; ++cf)
#pragma unroll
    for (int r = 0; r < 4; ++r){
      int row = r0 + kgrp*4 + r;
      int o = cf*16 + li;
      part[((size_t)sl*TN + row)*TOUT + o] = acc[cf][r];
    }
}

// ---------------- combine layer-2 partials -> output ----------------
__global__ void k_comb2(const float* __restrict__ part, const float* __restrict__ sums,
                        float* __restrict__ out){
  int t = blockIdx.x*256 + threadIdx.x;  // 131072
  int o4 = t & 15, n = (t >> 4) & 4095, b = t >> 16;
  f4 a = {0.f,0.f,0.f,0.f};
  float s = 0.f;
#pragma unroll
  for (int js = 0; js < 8; ++js){
    int sl = js*2 + b;
    a += ((const f4*)part)[((size_t)sl*TN + n)*16 + o4];
    s += sums[(size_t)sl*TN + n];
  }
  f4 r = a / s;
  ((f4*)out)[((size_t)(b*TN + n))*16 + o4] = r;
}

extern "C" void kernel_launch(void* const* d_in, const int* in_sizes, int n_in,
                              void* d_out, int out_size, void* d_ws, size_t ws_size,
                              hipStream_t stream) {
  (void)in_sizes; (void)n_in; (void)out_size; (void)ws_size;
  const float* x       = (const float*)d_in[0];
  const int*   adj     = (const int*)d_in[1];
  const float* W_heads = (const float*)d_in[2];
  const float* a1h     = (const float*)d_in[3];
  const float* a2h     = (const float*)d_in[4];
  const float* W_out   = (const float*)d_in[5];
  const float* a1o     = (const float*)d_in[6];
  const float* a2o     = (const float*)d_in[7];

  char* p = (char*)d_ws;
  auto alloc = [&](size_t sz){ char* r = p; p += (sz + 255) & ~(size_t)255; return r; };
  unsigned* adjp  = (unsigned*) alloc(4ull*1048576);       // 4 MB, live to end
  short*    wo    = (short*)    alloc(2ull*32768);
  short*    hTb   = (short*)    alloc(2ull*4194304);       // bf16 h^T [B][H][HID][N]
  float*    f1    = (float*)    alloc(4ull*32768);
  float*    Qa    = (float*)    alloc(4ull*32768);
  float*    Sa    = (float*)    alloc(4ull*32768);
  unsigned* mx    = (unsigned*) alloc(4ull*16);            // [0..7]=layer1, [8..9]=layer2
  short*    xcat  = (short*)    alloc(2ull*4194304);
  float*    f1o   = (float*)    alloc(4ull*8192);
  float*    Q2    = (float*)    alloc(4ull*8192);
  float*    S2    = (float*)    alloc(4ull*8192);
  short*    h2T   = (short*)    alloc(2ull*524288);
  float*    sums1 = (float*)    alloc(4ull*131072);        // 32 slices x 4096
  float*    sums2 = (float*)    alloc(4ull*65536);
  // union A: {xh, xl} (dead after k_gemm1) vs part1 bf16 (written by k_attn1)
  char* A = alloc(33554432ull);
  short* xh   = (short*)A;
  short* xl   = (short*)(A + 8388608);
  short* part1 = (short*)A;   // 32 sl x 4096 x 128 x 2B = 32 MB
  // union B: {wh, wl} (dead after k_gemm1) vs part2 (written by k_attn2)
  char* Bu = alloc(16777216ull);
  short* wh = (short*)Bu;
  short* wl = (short*)(Bu + 524288);
  float* part2 = (float*)Bu;

  k_pack <<<4096, 256, 0, stream>>>(adj, adjp, mx);
  k_split<<<4096, 256, 0, stream>>>(x, xh, xl);
  k_split<<<256, 256, 0, stream>>>(W_heads, wh, wl);
  k_cvt  <<<32, 256, 0, stream>>>(W_out, wo);
  k_gemm1<<<256, 512, 0, stream>>>(xh, xl, wh, wl, a1h, a2h, hTb, f1, Qa, Sa, mx);
  k_attn1<<<1024, 256, 0, stream>>>(hTb, f1, Qa, Sa, adjp, mx, part1, sums1);
  k_comb1<<<2048, 256, 0, stream>>>(part1, sums1, xcat);
  k_gemm2<<<256, 128, 0, stream>>>(xcat, wo, a1o, a2o, h2T, f1o, Q2, S2, mx + 8);
  k_attn2<<<1024, 256, 0, stream>>>(h2T, f1o, Q2, S2, adjp, mx + 8, part2, sums2);
  k_comb2<<<512, 256, 0, stream>>>(part2, sums2, (float*)d_out);
}

// Round 6
// 153.643 us; speedup vs baseline: 1.0055x; 1.0055x over previous
//
#include <hip/hip_runtime.h>

#define TB 2
#define TN 4096
#define TH 4
#define THID 128
#define TOUT 64
#define NW 128   // N/32 bitmask words per row

using f4    = __attribute__((ext_vector_type(4))) float;
using s16x8 = __attribute__((ext_vector_type(8))) short;
using s16x4 = __attribute__((ext_vector_type(4))) short;
using u32x4 = __attribute__((ext_vector_type(4))) unsigned;

static __device__ __forceinline__ short f2bf(float f){
  unsigned u = __float_as_uint(f);
  unsigned r = u + 0x7FFFu + ((u >> 16) & 1u);
  return (short)(r >> 16);
}
static __device__ __forceinline__ float bf2f(short s){
  return __uint_as_float(((unsigned)(unsigned short)s) << 16);
}
static __device__ __forceinline__ unsigned encf(float f){
  unsigned u = __float_as_uint(f);
  return (u & 0x80000000u) ? ~u : (u | 0x80000000u);
}
static __device__ __forceinline__ float decf(unsigned u){
  unsigned v = (u & 0x80000000u) ? (u & 0x7FFFFFFFu) : ~u;
  return __uint_as_float(v);
}
static __device__ __forceinline__ void gll16(const void* g, void* l){
  __builtin_amdgcn_global_load_lds((const __attribute__((address_space(1))) unsigned int*)g,
                                   (__attribute__((address_space(3))) unsigned int*)l, 16, 0, 0);
}
static __device__ __forceinline__ f4 mfma_bf16(s16x8 a, s16x8 b, f4 c){
  return __builtin_amdgcn_mfma_f32_16x16x32_bf16(a, b, c, 0, 0, 0);
}

// ---------------- pack adjacency to bits, TRANSPOSED: adjT[b][word][n] (+ clear mx) ----------------
__global__ void k_pack(const int* __restrict__ adj, unsigned* __restrict__ adjT,
                       unsigned* __restrict__ mx){
  if (blockIdx.x == 0 && threadIdx.x < 16) mx[threadIdx.x] = 0;
  int t = blockIdx.x * 256 + threadIdx.x;          // 1,048,576 = B * NW * N
  int n = t & 4095, w = (t >> 12) & 127, b = t >> 19;
  const int4* p = (const int4*)(adj + ((size_t)(b*TN + n))*TN + w*32);  // 32 ints for (b,n,w)
  unsigned m = 0;
#pragma unroll
  for (int i = 0; i < 8; ++i){
    int4 v = p[i];
    m |= (v.x != 0 ? 1u : 0u) << (i*4+0);
    m |= (v.y != 0 ? 1u : 0u) << (i*4+1);
    m |= (v.z != 0 ? 1u : 0u) << (i*4+2);
    m |= (v.w != 0 ? 1u : 0u) << (i*4+3);
  }
  adjT[((size_t)(b*NW + w))*TN + n] = m;
}

// ---------------- f32 -> bf16 hi/lo split (x, W_heads) ----------------
__global__ void k_split(const float* __restrict__ x, short* __restrict__ hi, short* __restrict__ lo){
  int t = blockIdx.x * 256 + threadIdx.x;
  f4 v = ((const f4*)x)[t];
  s16x4 h, l;
#pragma unroll
  for (int e = 0; e < 4; ++e){
    short hb = f2bf(v[e]);
    h[e] = hb;
    l[e] = f2bf(v[e] - bf2f(hb));
  }
  ((s16x4*)hi)[t] = h;
  ((s16x4*)lo)[t] = l;
}
// ---------------- f32 -> bf16 (W_out) ----------------
__global__ void k_cvt(const float* __restrict__ x, short* __restrict__ o){
  int t = blockIdx.x * 256 + threadIdx.x;
  f4 v = ((const f4*)x)[t];
  s16x4 h;
#pragma unroll
  for (int e = 0; e < 4; ++e) h[e] = f2bf(v[e]);
  ((s16x4*)o)[t] = h;
}

// ---------------- layer-1 projection + f1/f2/exp epilogue (split bf16, ~f32 acc) ----------------
// grid 256 = (nblk 4)*(mblk 64), 512 thr. C rows = n_out(512), cols = m(8192).
__global__ __launch_bounds__(512, 2) void k_gemm1(
    const short* __restrict__ xh, const short* __restrict__ xl,
    const short* __restrict__ wh, const short* __restrict__ wl,
    const float* __restrict__ a1h, const float* __restrict__ a2h,
    short* __restrict__ hTb, float* __restrict__ f1g,
    float* __restrict__ Qa, float* __restrict__ Sa, unsigned* __restrict__ mx){
  __shared__ short tiles[2][4][8192];  // dbuf x {Ah, Al (W), Bh, Bl (x)}: [128][64] swizzled
  __shared__ float red[2][128][2];
  __shared__ float bmx[2];
  int tid = threadIdx.x, lane = tid & 63, w = tid >> 6;
  int kgrp = lane >> 4, li = lane & 15;
  int nblk = blockIdx.x >> 6, mblk = blockIdx.x & 63;
  int n0 = nblk * 128, m0 = mblk * 128;
  int wn = w >> 2, wm = w & 3;
  const f4 fz = {0.f, 0.f, 0.f, 0.f};
  f4 acc[4][2];
#pragma unroll
  for (int i = 0; i < 4; ++i)
#pragma unroll
    for (int j = 0; j < 2; ++j) acc[i][j] = fz;

  // prologue: stage kt=0
#pragma unroll
  for (int tno = 0; tno < 4; ++tno){
    const short* gb = (tno==0 ? wh : tno==1 ? wl : tno==2 ? xh : xl);
    int r0 = (tno < 2) ? n0 : m0;
#pragma unroll
    for (int i = 0; i < 2; ++i){
      int s = (i*8 + w)*64 + lane;
      int row = s >> 3, c = s & 7, cs = c ^ (row & 7);
      gll16(gb + (size_t)(r0 + row)*512 + cs*8, (char*)tiles[0][tno] + (i*8+w)*1024);
    }
  }
  asm volatile("s_waitcnt vmcnt(0)" ::: "memory");
  __syncthreads();

  for (int kt = 0; kt < 8; ++kt){
    int cur = kt & 1;
    if (kt < 7){
      int k0 = (kt+1) * 64;
#pragma unroll
      for (int tno = 0; tno < 4; ++tno){
        const short* gb = (tno==0 ? wh : tno==1 ? wl : tno==2 ? xh : xl);
        int r0 = (tno < 2) ? n0 : m0;
#pragma unroll
        for (int i = 0; i < 2; ++i){
          int s = (i*8 + w)*64 + lane;
          int row = s >> 3, c = s & 7, cs = c ^ (row & 7);
          gll16(gb + (size_t)(r0 + row)*512 + k0 + cs*8, (char*)tiles[cur^1][tno] + (i*8+w)*1024);
        }
      }
    }
    const char* t0 = (const char*)tiles[cur][0];
    const char* t1 = (const char*)tiles[cur][1];
    const char* t2 = (const char*)tiles[cur][2];
    const char* t3 = (const char*)tiles[cur][3];
#pragma unroll
    for (int ks = 0; ks < 2; ++ks){
      int ck = ks*4 + kgrp;
      s16x8 ah[4], al[4], bh[2], bl[2];
#pragma unroll
      for (int fn = 0; fn < 4; ++fn){
        int row = wn*64 + fn*16 + li;
        int off = row*128 + ((ck ^ (row & 7)) << 4);
        ah[fn] = *(const s16x8*)(t0 + off);
        al[fn] = *(const s16x8*)(t1 + off);
      }
#pragma unroll
      for (int fm = 0; fm < 2; ++fm){
        int row = wm*32 + fm*16 + li;
        int off = row*128 + ((ck ^ (row & 7)) << 4);
        bh[fm] = *(const s16x8*)(t2 + off);
        bl[fm] = *(const s16x8*)(t3 + off);
      }
#pragma unroll
      for (int fn = 0; fn < 4; ++fn)
#pragma unroll
        for (int fm = 0; fm < 2; ++fm)
          acc[fn][fm] = mfma_bf16(ah[fn], bh[fm], acc[fn][fm]);
#pragma unroll
      for (int fn = 0; fn < 4; ++fn)
#pragma unroll
        for (int fm = 0; fm < 2; ++fm)
          acc[fn][fm] = mfma_bf16(ah[fn], bl[fm], acc[fn][fm]);
#pragma unroll
      for (int fn = 0; fn < 4; ++fn)
#pragma unroll
        for (int fm = 0; fm < 2; ++fm)
          acc[fn][fm] = mfma_bf16(al[fn], bh[fm], acc[fn][fm]);
    }
    asm volatile("s_waitcnt vmcnt(0)" ::: "memory");
    __syncthreads();
  }
  int head = nblk;
  // C write (bf16 hT)
#pragma unroll
  for (int fn = 0; fn < 4; ++fn){
#pragma unroll
    for (int fm = 0; fm < 2; ++fm){
#pragma unroll
      for (int r = 0; r < 4; ++r){
        int nout = n0 + wn*64 + fn*16 + kgrp*4 + r;
        int m = m0 + wm*32 + fm*16 + li;
        int b = m >> 12, n = m & 4095;
        int hid = nout & 127;
        size_t idx = ((size_t)((b*TH + head)*THID + hid))*TN + n;
        hTb[idx] = f2bf(acc[fn][fm][r]);
      }
    }
  }
  // fold f1 = h.a1, f2 = h.a2 from f32 acc
  const float* a1p = a1h + head*THID;
  const float* a2p = a2h + head*THID;
  float s1[2] = {0.f, 0.f}, s2[2] = {0.f, 0.f};
#pragma unroll
  for (int fn = 0; fn < 4; ++fn)
#pragma unroll
    for (int r = 0; r < 4; ++r){
      int row = wn*64 + fn*16 + kgrp*4 + r;
      float w1 = a1p[row], w2 = a2p[row];
#pragma unroll
      for (int fm = 0; fm < 2; ++fm){
        s1[fm] = fmaf(acc[fn][fm][r], w1, s1[fm]);
        s2[fm] = fmaf(acc[fn][fm][r], w2, s2[fm]);
      }
    }
#pragma unroll
  for (int fm = 0; fm < 2; ++fm){
    s1[fm] += __shfl_xor(s1[fm], 16); s1[fm] += __shfl_xor(s1[fm], 32);
    s2[fm] += __shfl_xor(s2[fm], 16); s2[fm] += __shfl_xor(s2[fm], 32);
  }
  if (kgrp == 0){
#pragma unroll
    for (int fm = 0; fm < 2; ++fm){
      int col = wm*32 + fm*16 + li;
      red[wn][col][0] = s1[fm];
      red[wn][col][1] = s2[fm];
    }
  }
  __syncthreads();
  if (tid < 128){
    float f1v = red[0][tid][0] + red[1][tid][0];
    float f2v = red[0][tid][1] + red[1][tid][1];
    int m = m0 + tid, b = m >> 12, n = m & 4095;
    int idx = (b*TH + head)*TN + n;
    f1g[idx] = f1v;
    Qa[idx] = expf(f2v);
    Sa[idx] = expf(0.2f*f2v);
    float wmx = f2v;
#pragma unroll
    for (int d = 1; d < 64; d <<= 1) wmx = fmaxf(wmx, __shfl_xor(wmx, d));
    if ((tid & 63) == 0) bmx[tid >> 6] = wmx;
  }
  __syncthreads();
  if (tid == 0){
    int b = m0 >> 12;
    atomicMax(&mx[b*TH + head], encf(fmaxf(bmx[0], bmx[1])));
  }
}

// ---------------- layer-1 fused attention: 4-deep counted-vmcnt pipeline ----------------
// grid 1024 = (js 4)*(b 2)*(h 4)*(rblk 32); 4 waves x 32 rows x 128 cols
__global__ __launch_bounds__(256, 2) void k_attn1(
    const short* __restrict__ hTb, const float* __restrict__ f1,
    const float* __restrict__ Qa, const float* __restrict__ Sa,
    const unsigned* __restrict__ adjT, const unsigned* __restrict__ mx,
    short* __restrict__ part, float* __restrict__ sums){
  __shared__ short tile[4][8192];       // 64 KB: [128 hid][64 j] swizzled, 4-deep
  __shared__ float Qs[1024], Ss[1024];  // 8 KB (full js-slice)
  __shared__ unsigned abuf[4][256];     // 4 KB: [word 2][row 128] per tile
  int tid = threadIdx.x, lane = tid & 63, w = tid >> 6;   // w in 0..3
  int kgrp = lane >> 4, li = lane & 15;
  int bid = blockIdx.x;
  int js = bid >> 8, b = (bid >> 7) & 1, h = (bid >> 5) & 3, rblk = bid & 31;
  int bh = b*TH + h;
  int jbase = js * 1024;
  int r0b = rblk * 128;
  const short* hbase = hTb + ((size_t)bh*THID)*TN;
  const float* Qrow = Qa + (size_t)bh*TN + jbase;
  const float* Srow = Sa + (size_t)bh*TN + jbase;

  auto STAGE = [&](int t){
    int jg = jbase + t*64;
    char* dst = (char*)tile[t & 3];
#pragma unroll
    for (int i = 0; i < 4; ++i){
      int s = (i*4 + w)*64 + lane;
      int row = s >> 3, c = s & 7, cs = c ^ (row & 7);
      gll16(hbase + (size_t)row*TN + jg + cs*8, dst + (i*4+w)*1024);
    }
    // adjacency words for this tile (redundant across waves -> uniform vmcnt)
    int w0 = jg >> 5;
    gll16(adjT + (size_t)(b*NW + w0 + (lane>>5))*TN + r0b + (lane&31)*4, (char*)abuf[t & 3]);
  };

  // prologue: Q/S (2 ops) then tiles 0..2 (5 ops each) -> 17 outstanding
  gll16(Qrow + w*256 + lane*4, (char*)Qs + w*1024);
  gll16(Srow + w*256 + lane*4, (char*)Ss + w*1024);
  STAGE(0); STAGE(1); STAGE(2);

  int r0 = r0b + w*32;
  float Pv[2], Rv[2];
  int lrow[2];
  float mf = decf(mx[bh]);
#pragma unroll
  for (int rf = 0; rf < 2; ++rf){
    int row = r0 + rf*16 + li;
    lrow[rf] = w*32 + rf*16 + li;
    float f1v = f1[bh*TN + row];
    float e = f1v + mf;
    float m = e > 0.f ? e : 0.2f*e;       // leaky upper bound of all scores in row
    Pv[rf] = expf(f1v - m);
    Rv[rf] = expf(0.2f*f1v - m);
  }
  const f4 fz = {0.f,0.f,0.f,0.f};
  f4 acc[2][8];
#pragma unroll
  for (int i = 0; i < 2; ++i)
#pragma unroll
    for (int j = 0; j < 8; ++j) acc[i][j] = fz;
  f4 accs[2] = {fz, fz};
  s16x8 ones;
#pragma unroll
  for (int e = 0; e < 8; ++e) ones[e] = (short)0x3F80;

  for (int jt = 0; jt < 16; ++jt){
    // counted wait: keep 2 tiles (5 ops each) in flight; never drain mid-loop
    if (jt < 14)       asm volatile("s_waitcnt vmcnt(10)" ::: "memory");
    else if (jt == 14) asm volatile("s_waitcnt vmcnt(5)" ::: "memory");
    else               asm volatile("s_waitcnt vmcnt(0)" ::: "memory");
    __builtin_amdgcn_s_barrier();
    __builtin_amdgcn_sched_barrier(0);
    if (jt < 13) STAGE(jt + 3);

    int j0 = jt*64;
    const char* tp = (const char*)tile[jt & 3];
    const unsigned* ab = abuf[jt & 3];
    unsigned aw0[2], aw1[2];
#pragma unroll
    for (int rf = 0; rf < 2; ++rf){
      aw0[rf] = ab[lrow[rf]];        // ks=0 word
      aw1[rf] = ab[128 + lrow[rf]];  // ks=1 word
    }
#pragma unroll
    for (int ks = 0; ks < 2; ++ks){
      int jloc = j0 + ks*32 + kgrp*8;
      float qv[8], sv[8];
      *(f4*)&qv[0] = *(const f4*)&Qs[jloc];
      *(f4*)&qv[4] = *(const f4*)&Qs[jloc+4];
      *(f4*)&sv[0] = *(const f4*)&Ss[jloc];
      *(f4*)&sv[4] = *(const f4*)&Ss[jloc+4];
      s16x8 af[2];
#pragma unroll
      for (int rf = 0; rf < 2; ++rf){
        unsigned word = ks ? aw1[rf] : aw0[rf];
        unsigned byt = (word >> (kgrp*8)) & 0xFFu;
        float P = Pv[rf], R = Rv[rf];
        u32x4 pw;
#pragma unroll
        for (int pe = 0; pe < 4; ++pe){
          float va = fmaxf(P*qv[2*pe],   R*sv[2*pe]);
          float vb = fmaxf(P*qv[2*pe+1], R*sv[2*pe+1]);
          va = (byt & (1u << (2*pe)))   ? va : 0.f;
          vb = (byt & (1u << (2*pe+1))) ? vb : 0.f;
          unsigned ua = __float_as_uint(va) + 0x8000u;  // round-half-up to bf16
          unsigned ub = __float_as_uint(vb) + 0x8000u;
          pw[pe] = __builtin_amdgcn_perm(ub, ua, 0x07060302); // pack hi16s
        }
        af[rf] = __builtin_bit_cast(s16x8, pw);
      }
      accs[0] = mfma_bf16(af[0], ones, accs[0]);  // row sums via MFMA
      accs[1] = mfma_bf16(af[1], ones, accs[1]);
#pragma unroll
      for (int cf = 0; cf < 8; ++cf){
        int col = cf*16 + li;
        int off = col*128 + (((ks*4 + kgrp) ^ (col & 7)) << 4);
        s16x8 bfr = *(const s16x8*)(tp + off);
        acc[0][cf] = mfma_bf16(af[0], bfr, acc[0][cf]);
        acc[1][cf] = mfma_bf16(af[1], bfr, acc[1][cf]);
      }
    }
  }
  int sl = js*8 + bh;
  if (li == 0){
#pragma unroll
    for (int rf = 0; rf < 2; ++rf)
#pragma unroll
      for (int r = 0; r < 4; ++r)
        sums[(size_t)sl*TN + r0 + rf*16 + kgrp*4 + r] = accs[rf][r];
  }
#pragma unroll
  for (int rf = 0; rf < 2; ++rf)
#pragma unroll
    for (int cf = 0; cf < 8; ++cf)
#pragma unroll
      for (int r = 0; r < 4; ++r){
        int row = r0 + rf*16 + kgrp*4 + r;
        int hid = cf*16 + li;
        part[((size_t)sl*TN + row)*THID + hid] = f2bf(acc[rf][cf][r]);
      }
}

// ---------------- combine layer-1 partials (bf16, 4 slices) -> x_cat (ELU, bf16) ----------------
__global__ void k_comb1(const short* __restrict__ part, const float* __restrict__ sums,
                        short* __restrict__ xcat){
  int t = blockIdx.x*256 + threadIdx.x;   // 524,288
  int hid8 = t & 15, n = (t >> 4) & 4095, h = (t >> 16) & 3, b = t >> 18;
  int bh = b*TH + h;
  float a[8] = {0,0,0,0,0,0,0,0};
  float s = 0.f;
#pragma unroll
  for (int js = 0; js < 4; ++js){
    size_t rowoff = (size_t)(js*8 + bh)*TN + n;
    s16x8 pv = *(const s16x8*)(part + rowoff*THID + hid8*8);
#pragma unroll
    for (int e = 0; e < 8; ++e) a[e] += bf2f(pv[e]);
    s += sums[rowoff];
  }
  float inv = 1.f / s;
  s16x8 o;
#pragma unroll
  for (int e = 0; e < 8; ++e){
    float x = a[e] * inv;
    o[e] = f2bf(x > 0.f ? x : expm1f(x));
  }
  *(s16x8*)(xcat + ((size_t)(b*TN + n))*512 + h*128 + hid8*8) = o;
}

// ---------------- layer-2 projection + f1o/f2o ----------------
// grid 256, 128 thr (2 waves x 16 rows), cols = 64
__global__ __launch_bounds__(128) void k_gemm2(
    const short* __restrict__ xcat, const short* __restrict__ wo,
    const float* __restrict__ a1o, const float* __restrict__ a2o,
    short* __restrict__ h2T, float* __restrict__ f1o,
    float* __restrict__ Q2, float* __restrict__ S2, unsigned* __restrict__ mx2){
  int tid = threadIdx.x, lane = tid & 63, w = tid >> 6;
  int kgrp = lane >> 4, li = lane & 15;
  int m0 = blockIdx.x * 32;
  const f4 fz = {0.f,0.f,0.f,0.f};
  f4 acc[4] = {fz, fz, fz, fz};
  int rowA = m0 + w*16 + li;
  for (int kt = 0; kt < 16; ++kt){
    int k = kt*32 + kgrp*8;
    s16x8 a = *(const s16x8*)(xcat + (size_t)rowA*512 + k);
#pragma unroll
    for (int cf = 0; cf < 4; ++cf){
      int col = cf*16 + li;
      s16x8 bfr = *(const s16x8*)(wo + (size_t)col*512 + k);
      acc[cf] = mfma_bf16(a, bfr, acc[cf]);
    }
  }
  float p1[4] = {0,0,0,0}, p2[4] = {0,0,0,0};
#pragma unroll
  for (int cf = 0; cf < 4; ++cf){
    int o = cf*16 + li;
    float w1 = a1o[o], w2 = a2o[o];
#pragma unroll
    for (int r = 0; r < 4; ++r){
      p1[r] = fmaf(acc[cf][r], w1, p1[r]);
      p2[r] = fmaf(acc[cf][r], w2, p2[r]);
    }
  }
#pragma unroll
  for (int r = 0; r < 4; ++r){
#pragma unroll
    for (int d = 1; d < 16; d <<= 1){
      p1[r] += __shfl_xor(p1[r], d);
      p2[r] += __shfl_xor(p2[r], d);
    }
  }
#pragma unroll
  for (int cf = 0; cf < 4; ++cf)
#pragma unroll
    for (int r = 0; r < 4; ++r){
      int row = m0 + w*16 + kgrp*4 + r;
      int o = cf*16 + li;
      int b = row >> 12, n = row & 4095;
      h2T[((size_t)(b*TOUT + o))*TN + n] = f2bf(acc[cf][r]);
    }
  if (li == 0){
#pragma unroll
    for (int r = 0; r < 4; ++r){
      int row = m0 + w*16 + kgrp*4 + r;   // row == b*N + n
      f1o[row] = p1[r];
      Q2[row] = expf(p2[r]);
      S2[row] = expf(0.2f*p2[r]);
    }
  }
  float m2 = fmaxf(fmaxf(p2[0], p2[1]), fmaxf(p2[2], p2[3]));
  m2 = fmaxf(m2, __shfl_xor(m2, 16));
  m2 = fmaxf(m2, __shfl_xor(m2, 32));
  __shared__ float bm[2];
  if (lane == 0) bm[w] = m2;
  __syncthreads();
  if (tid == 0) atomicMax(&mx2[m0 >> 12], encf(fmaxf(bm[0], bm[1])));
}

// ---------------- layer-2 fused attention: 4-deep counted-vmcnt pipeline ----------------
// grid 512 = (js 4)*(b 2)*(rblk 64); 4 waves x 16 rows x 64 cols
__global__ __launch_bounds__(256, 3) void k_attn2(
    const short* __restrict__ h2T, const float* __restrict__ f1o,
    const float* __restrict__ Q2, const float* __restrict__ S2,
    const unsigned* __restrict__ adjT, const unsigned* __restrict__ mx2,
    float* __restrict__ part, float* __restrict__ sums){
  __shared__ short tile[4][4096];       // 32 KB: [64 o][64 j] swizzled, 4-deep
  __shared__ float Qs[1024], Ss[1024];  // 8 KB
  __shared__ unsigned abuf[4][128];     // 2 KB: [word 2][row 64] per tile
  int tid = threadIdx.x, lane = tid & 63, w = tid >> 6;  // w in 0..3
  int kgrp = lane >> 4, li = lane & 15;
  int bid = blockIdx.x;
  int js = bid >> 7, b = (bid >> 6) & 1, rblk = bid & 63;
  int jbase = js * 1024;
  int r0b = rblk * 64;
  const short* hbase = h2T + (size_t)b*TOUT*TN;
  const float* Qrow = Q2 + (size_t)b*TN + jbase;
  const float* Srow = S2 + (size_t)b*TN + jbase;

  auto STAGE = [&](int t){
    int jg = jbase + t*64;
    char* dst = (char*)tile[t & 3];
#pragma unroll
    for (int i = 0; i < 2; ++i){
      int s = (i*4 + w)*64 + lane;
      int row = s >> 3, c = s & 7, cs = c ^ (row & 7);
      gll16(hbase + (size_t)row*TN + jg + cs*8, dst + (i*4+w)*1024);
    }
    int w0 = jg >> 5;
    if (lane < 32)
      gll16(adjT + (size_t)(b*NW + w0 + (lane>>4))*TN + r0b + (lane&15)*4, (char*)abuf[t & 3]);
  };

  gll16(Qrow + w*256 + lane*4, (char*)Qs + w*1024);
  gll16(Srow + w*256 + lane*4, (char*)Ss + w*1024);
  STAGE(0); STAGE(1); STAGE(2);

  int r0 = r0b + w*16;
  int lrow = w*16 + li;
  float mf = decf(mx2[b]);
  float f1v = f1o[b*TN + r0 + li];
  float e0 = f1v + mf;
  float m0v = e0 > 0.f ? e0 : 0.2f*e0;
  float Pv = expf(f1v - m0v);
  float Rv = expf(0.2f*f1v - m0v);
  const f4 fz = {0.f,0.f,0.f,0.f};
  f4 acc[4] = {fz, fz, fz, fz};
  f4 accs = fz;
  s16x8 ones;
#pragma unroll
  for (int e = 0; e < 8; ++e) ones[e] = (short)0x3F80;

  for (int jt = 0; jt < 16; ++jt){
    if (jt < 14)       asm volatile("s_waitcnt vmcnt(6)" ::: "memory");
    else if (jt == 14) asm volatile("s_waitcnt vmcnt(3)" ::: "memory");
    else               asm volatile("s_waitcnt vmcnt(0)" ::: "memory");
    __builtin_amdgcn_s_barrier();
    __builtin_amdgcn_sched_barrier(0);
    if (jt < 13) STAGE(jt + 3);

    int j0 = jt*64;
    const char* tp = (const char*)tile[jt & 3];
    const unsigned* ab = abuf[jt & 3];
    unsigned aw0 = ab[lrow], aw1 = ab[64 + lrow];
#pragma unroll
    for (int ks = 0; ks < 2; ++ks){
      int jloc = j0 + ks*32 + kgrp*8;
      float qv[8], sv[8];
      *(f4*)&qv[0] = *(const f4*)&Qs[jloc];
      *(f4*)&qv[4] = *(const f4*)&Qs[jloc+4];
      *(f4*)&sv[0] = *(const f4*)&Ss[jloc];
      *(f4*)&sv[4] = *(const f4*)&Ss[jloc+4];
      unsigned word = ks ? aw1 : aw0;
      unsigned byt = (word >> (kgrp*8)) & 0xFFu;
      u32x4 pw;
#pragma unroll
      for (int pe = 0; pe < 4; ++pe){
        float va = fmaxf(Pv*qv[2*pe],   Rv*sv[2*pe]);
        float vb = fmaxf(Pv*qv[2*pe+1], Rv*sv[2*pe+1]);
        va = (byt & (1u << (2*pe)))   ? va : 0.f;
        vb = (byt & (1u << (2*pe+1))) ? vb : 0.f;
        unsigned ua = __float_as_uint(va) + 0x8000u;
        unsigned ub = __float_as_uint(vb) + 0x8000u;
        pw[pe] = __builtin_amdgcn_perm(ub, ua, 0x07060302);
      }
      s16x8 af = __builtin_bit_cast(s16x8, pw);
      accs = mfma_bf16(af, ones, accs);
#pragma unroll
      for (int cf = 0; cf < 4; ++cf){
        int col = cf*16 + li;
        int off = col*128 + (((ks*4 + kgrp) ^ (col & 7)) << 4);
        s16x8 bfr = *(const s16x8*)(tp + off);
        acc[cf] = mfma_bf16(af, bfr, acc[cf]);
      }
    }
  }
  int sl = js*2 + b;
  if (li == 0){
#pragma unroll
    for (int r = 0; r < 4; ++r)
      sums[(size_t)sl*TN + r0 + kgrp*4 + r] = accs[r];
  }
#pragma unroll
  for (int cf = 0; cf < 4; ++cf)
#pragma unroll
    for (int r = 0; r < 4; ++r){
      int row = r0 + kgrp*4 + r;
      int o = cf*16 + li;
      part[((size_t)sl*TN + row)*TOUT + o] = acc[cf][r];
    }
}

// ---------------- combine layer-2 partials -> output ----------------
__global__ void k_comb2(const float* __restrict__ part, const float* __restrict__ sums,
                        float* __restrict__ out){
  int t = blockIdx.x*256 + threadIdx.x;  // 131072
  int o4 = t & 15, n = (t >> 4) & 4095, b = t >> 16;
  f4 a = {0.f,0.f,0.f,0.f};
  float s = 0.f;
#pragma unroll
  for (int js = 0; js < 4; ++js){
    int sl = js*2 + b;
    a += ((const f4*)part)[((size_t)sl*TN + n)*16 + o4];
    s += sums[(size_t)sl*TN + n];
  }
  f4 r = a / s;
  ((f4*)out)[((size_t)(b*TN + n))*16 + o4] = r;
}

extern "C" void kernel_launch(void* const* d_in, const int* in_sizes, int n_in,
                              void* d_out, int out_size, void* d_ws, size_t ws_size,
                              hipStream_t stream) {
  (void)in_sizes; (void)n_in; (void)out_size; (void)ws_size;
  const float* x       = (const float*)d_in[0];
  const int*   adj     = (const int*)d_in[1];
  const float* W_heads = (const float*)d_in[2];
  const float* a1h     = (const float*)d_in[3];
  const float* a2h     = (const float*)d_in[4];
  const float* W_out   = (const float*)d_in[5];
  const float* a1o     = (const float*)d_in[6];
  const float* a2o     = (const float*)d_in[7];

  char* p = (char*)d_ws;
  auto alloc = [&](size_t sz){ char* r = p; p += (sz + 255) & ~(size_t)255; return r; };
  unsigned* adjT  = (unsigned*) alloc(4ull*1048576);       // 4 MB transposed bitmask, live to end
  short*    wo    = (short*)    alloc(2ull*32768);
  short*    hTb   = (short*)    alloc(2ull*4194304);       // bf16 h^T [B][H][HID][N]
  float*    f1    = (float*)    alloc(4ull*32768);
  float*    Qa    = (float*)    alloc(4ull*32768);
  float*    Sa    = (float*)    alloc(4ull*32768);
  unsigned* mx    = (unsigned*) alloc(4ull*16);            // [0..7]=layer1, [8..9]=layer2
  short*    xcat  = (short*)    alloc(2ull*4194304);
  float*    f1o   = (float*)    alloc(4ull*8192);
  float*    Q2    = (float*)    alloc(4ull*8192);
  float*    S2    = (float*)    alloc(4ull*8192);
  short*    h2T   = (short*)    alloc(2ull*524288);
  float*    sums1 = (float*)    alloc(4ull*131072);        // 32 slices x 4096
  float*    sums2 = (float*)    alloc(4ull*65536);
  // union A: {xh, xl} (dead after k_gemm1) vs part1 bf16 (written by k_attn1)
  char* A = alloc(33554432ull);
  short* xh   = (short*)A;
  short* xl   = (short*)(A + 8388608);
  short* part1 = (short*)A;   // 32 sl x 4096 x 128 x 2B = 32 MB
  // union B: {wh, wl} (dead after k_gemm1) vs part2 (written by k_attn2)
  char* Bu = alloc(16777216ull);
  short* wh = (short*)Bu;
  short* wl = (short*)(Bu + 524288);
  float* part2 = (float*)Bu;  // 8 sl x 4096 x 64 x 4B = 8 MB

  k_pack <<<4096, 256, 0, stream>>>(adj, adjT, mx);
  k_split<<<4096, 256, 0, stream>>>(x, xh, xl);
  k_split<<<256, 256, 0, stream>>>(W_heads, wh, wl);
  k_cvt  <<<32, 256, 0, stream>>>(W_out, wo);
  k_gemm1<<<256, 512, 0, stream>>>(xh, xl, wh, wl, a1h, a2h, hTb, f1, Qa, Sa, mx);
  k_attn1<<<1024, 256, 0, stream>>>(hTb, f1, Qa, Sa, adjT, mx, part1, sums1);
  k_comb1<<<2048, 256, 0, stream>>>(part1, sums1, xcat);
  k_gemm2<<<256, 128, 0, stream>>>(xcat, wo, a1o, a2o, h2T, f1o, Q2, S2, mx + 8);
  k_attn2<<<512, 256, 0, stream>>>(h2T, f1o, Q2, S2, adjT, mx + 8, part2, sums2);
  k_comb2<<<512, 256, 0, stream>>>(part2, sums2, (float*)d_out);
}

// Round 7
// 148.035 us; speedup vs baseline: 1.0436x; 1.0379x over previous
//
#include <hip/hip_runtime.h>

#define TB 2
#define TN 4096
#define TH 4
#define THID 128
#define TOUT 64
#define NW 128   // N/32 bitmask words per row

using f4    = __attribute__((ext_vector_type(4))) float;
using s16x8 = __attribute__((ext_vector_type(8))) short;
using s16x4 = __attribute__((ext_vector_type(4))) short;
using u32x4 = __attribute__((ext_vector_type(4))) unsigned;

static __device__ __forceinline__ short f2bf(float f){
  unsigned u = __float_as_uint(f);
  unsigned r = u + 0x7FFFu + ((u >> 16) & 1u);
  return (short)(r >> 16);
}
static __device__ __forceinline__ float bf2f(short s){
  return __uint_as_float(((unsigned)(unsigned short)s) << 16);
}
static __device__ __forceinline__ unsigned encf(float f){
  unsigned u = __float_as_uint(f);
  return (u & 0x80000000u) ? ~u : (u | 0x80000000u);
}
static __device__ __forceinline__ float decf(unsigned u){
  unsigned v = (u & 0x80000000u) ? (u & 0x7FFFFFFFu) : ~u;
  return __uint_as_float(v);
}
static __device__ __forceinline__ void gll16(const void* g, void* l){
  __builtin_amdgcn_global_load_lds((const __attribute__((address_space(1))) unsigned int*)g,
                                   (__attribute__((address_space(3))) unsigned int*)l, 16, 0, 0);
}
static __device__ __forceinline__ f4 mfma_bf16(s16x8 a, s16x8 b, f4 c){
  return __builtin_amdgcn_mfma_f32_16x16x32_bf16(a, b, c, 0, 0, 0);
}

// ---------------- pack adjacency to bits, TRANSPOSED: adjT[b][word][n] (+ clear mx) ----------------
__global__ void k_pack(const int* __restrict__ adj, unsigned* __restrict__ adjT,
                       unsigned* __restrict__ mx){
  if (blockIdx.x == 0 && threadIdx.x < 16) mx[threadIdx.x] = 0;
  int t = blockIdx.x * 256 + threadIdx.x;          // 1,048,576 = B * NW * N
  int n = t & 4095, w = (t >> 12) & 127, b = t >> 19;
  const int4* p = (const int4*)(adj + ((size_t)(b*TN + n))*TN + w*32);  // 32 ints for (b,n,w)
  unsigned m = 0;
#pragma unroll
  for (int i = 0; i < 8; ++i){
    int4 v = p[i];
    m |= (v.x != 0 ? 1u : 0u) << (i*4+0);
    m |= (v.y != 0 ? 1u : 0u) << (i*4+1);
    m |= (v.z != 0 ? 1u : 0u) << (i*4+2);
    m |= (v.w != 0 ? 1u : 0u) << (i*4+3);
  }
  adjT[((size_t)(b*NW + w))*TN + n] = m;
}

// ---------------- f32 -> bf16 hi/lo split (x, W_heads) ----------------
__global__ void k_split(const float* __restrict__ x, short* __restrict__ hi, short* __restrict__ lo){
  int t = blockIdx.x * 256 + threadIdx.x;
  f4 v = ((const f4*)x)[t];
  s16x4 h, l;
#pragma unroll
  for (int e = 0; e < 4; ++e){
    short hb = f2bf(v[e]);
    h[e] = hb;
    l[e] = f2bf(v[e] - bf2f(hb));
  }
  ((s16x4*)hi)[t] = h;
  ((s16x4*)lo)[t] = l;
}
// ---------------- f32 -> bf16 (W_out) ----------------
__global__ void k_cvt(const float* __restrict__ x, short* __restrict__ o){
  int t = blockIdx.x * 256 + threadIdx.x;
  f4 v = ((const f4*)x)[t];
  s16x4 h;
#pragma unroll
  for (int e = 0; e < 4; ++e) h[e] = f2bf(v[e]);
  ((s16x4*)o)[t] = h;
}

// ---------------- layer-1 projection + f1/f2/exp epilogue (split bf16, ~f32 acc) ----------------
// grid 256 = (nblk 4)*(mblk 64), 512 thr. C rows = n_out(512), cols = m(8192).
__global__ __launch_bounds__(512, 2) void k_gemm1(
    const short* __restrict__ xh, const short* __restrict__ xl,
    const short* __restrict__ wh, const short* __restrict__ wl,
    const float* __restrict__ a1h, const float* __restrict__ a2h,
    short* __restrict__ hTb, float* __restrict__ f1g,
    float* __restrict__ Qa, float* __restrict__ Sa, unsigned* __restrict__ mx){
  __shared__ short tiles[2][4][8192];  // dbuf x {Ah, Al (W), Bh, Bl (x)}: [128][64] swizzled
  __shared__ float red[2][128][2];
  __shared__ float bmx[2];
  int tid = threadIdx.x, lane = tid & 63, w = tid >> 6;
  int kgrp = lane >> 4, li = lane & 15;
  int nblk = blockIdx.x >> 6, mblk = blockIdx.x & 63;
  int n0 = nblk * 128, m0 = mblk * 128;
  int wn = w >> 2, wm = w & 3;
  const f4 fz = {0.f, 0.f, 0.f, 0.f};
  f4 acc[4][2];
#pragma unroll
  for (int i = 0; i < 4; ++i)
#pragma unroll
    for (int j = 0; j < 2; ++j) acc[i][j] = fz;

  // prologue: stage kt=0
#pragma unroll
  for (int tno = 0; tno < 4; ++tno){
    const short* gb = (tno==0 ? wh : tno==1 ? wl : tno==2 ? xh : xl);
    int r0 = (tno < 2) ? n0 : m0;
#pragma unroll
    for (int i = 0; i < 2; ++i){
      int s = (i*8 + w)*64 + lane;
      int row = s >> 3, c = s & 7, cs = c ^ (row & 7);
      gll16(gb + (size_t)(r0 + row)*512 + cs*8, (char*)tiles[0][tno] + (i*8+w)*1024);
    }
  }
  asm volatile("s_waitcnt vmcnt(0)" ::: "memory");
  __syncthreads();

  for (int kt = 0; kt < 8; ++kt){
    int cur = kt & 1;
    if (kt < 7){
      int k0 = (kt+1) * 64;
#pragma unroll
      for (int tno = 0; tno < 4; ++tno){
        const short* gb = (tno==0 ? wh : tno==1 ? wl : tno==2 ? xh : xl);
        int r0 = (tno < 2) ? n0 : m0;
#pragma unroll
        for (int i = 0; i < 2; ++i){
          int s = (i*8 + w)*64 + lane;
          int row = s >> 3, c = s & 7, cs = c ^ (row & 7);
          gll16(gb + (size_t)(r0 + row)*512 + k0 + cs*8, (char*)tiles[cur^1][tno] + (i*8+w)*1024);
        }
      }
    }
    const char* t0 = (const char*)tiles[cur][0];
    const char* t1 = (const char*)tiles[cur][1];
    const char* t2 = (const char*)tiles[cur][2];
    const char* t3 = (const char*)tiles[cur][3];
#pragma unroll
    for (int ks = 0; ks < 2; ++ks){
      int ck = ks*4 + kgrp;
      s16x8 ah[4], al[4], bh[2], bl[2];
#pragma unroll
      for (int fn = 0; fn < 4; ++fn){
        int row = wn*64 + fn*16 + li;
        int off = row*128 + ((ck ^ (row & 7)) << 4);
        ah[fn] = *(const s16x8*)(t0 + off);
        al[fn] = *(const s16x8*)(t1 + off);
      }
#pragma unroll
      for (int fm = 0; fm < 2; ++fm){
        int row = wm*32 + fm*16 + li;
        int off = row*128 + ((ck ^ (row & 7)) << 4);
        bh[fm] = *(const s16x8*)(t2 + off);
        bl[fm] = *(const s16x8*)(t3 + off);
      }
#pragma unroll
      for (int fn = 0; fn < 4; ++fn)
#pragma unroll
        for (int fm = 0; fm < 2; ++fm)
          acc[fn][fm] = mfma_bf16(ah[fn], bh[fm], acc[fn][fm]);
#pragma unroll
      for (int fn = 0; fn < 4; ++fn)
#pragma unroll
        for (int fm = 0; fm < 2; ++fm)
          acc[fn][fm] = mfma_bf16(ah[fn], bl[fm], acc[fn][fm]);
#pragma unroll
      for (int fn = 0; fn < 4; ++fn)
#pragma unroll
        for (int fm = 0; fm < 2; ++fm)
          acc[fn][fm] = mfma_bf16(al[fn], bh[fm], acc[fn][fm]);
    }
    asm volatile("s_waitcnt vmcnt(0)" ::: "memory");
    __syncthreads();
  }
  int head = nblk;
  // C write (bf16 hT)
#pragma unroll
  for (int fn = 0; fn < 4; ++fn){
#pragma unroll
    for (int fm = 0; fm < 2; ++fm){
#pragma unroll
      for (int r = 0; r < 4; ++r){
        int nout = n0 + wn*64 + fn*16 + kgrp*4 + r;
        int m = m0 + wm*32 + fm*16 + li;
        int b = m >> 12, n = m & 4095;
        int hid = nout & 127;
        size_t idx = ((size_t)((b*TH + head)*THID + hid))*TN + n;
        hTb[idx] = f2bf(acc[fn][fm][r]);
      }
    }
  }
  // fold f1 = h.a1, f2 = h.a2 from f32 acc
  const float* a1p = a1h + head*THID;
  const float* a2p = a2h + head*THID;
  float s1[2] = {0.f, 0.f}, s2[2] = {0.f, 0.f};
#pragma unroll
  for (int fn = 0; fn < 4; ++fn)
#pragma unroll
    for (int r = 0; r < 4; ++r){
      int row = wn*64 + fn*16 + kgrp*4 + r;
      float w1 = a1p[row], w2 = a2p[row];
#pragma unroll
      for (int fm = 0; fm < 2; ++fm){
        s1[fm] = fmaf(acc[fn][fm][r], w1, s1[fm]);
        s2[fm] = fmaf(acc[fn][fm][r], w2, s2[fm]);
      }
    }
#pragma unroll
  for (int fm = 0; fm < 2; ++fm){
    s1[fm] += __shfl_xor(s1[fm], 16); s1[fm] += __shfl_xor(s1[fm], 32);
    s2[fm] += __shfl_xor(s2[fm], 16); s2[fm] += __shfl_xor(s2[fm], 32);
  }
  if (kgrp == 0){
#pragma unroll
    for (int fm = 0; fm < 2; ++fm){
      int col = wm*32 + fm*16 + li;
      red[wn][col][0] = s1[fm];
      red[wn][col][1] = s2[fm];
    }
  }
  __syncthreads();
  if (tid < 128){
    float f1v = red[0][tid][0] + red[1][tid][0];
    float f2v = red[0][tid][1] + red[1][tid][1];
    int m = m0 + tid, b = m >> 12, n = m & 4095;
    int idx = (b*TH + head)*TN + n;
    f1g[idx] = f1v;
    Qa[idx] = expf(f2v);
    Sa[idx] = expf(0.2f*f2v);
    float wmx = f2v;
#pragma unroll
    for (int d = 1; d < 64; d <<= 1) wmx = fmaxf(wmx, __shfl_xor(wmx, d));
    if ((tid & 63) == 0) bmx[tid >> 6] = wmx;
  }
  __syncthreads();
  if (tid == 0){
    int b = m0 >> 12;
    atomicMax(&mx[b*TH + head], encf(fmaxf(bmx[0], bmx[1])));
  }
}

// ---------------- layer-1 fused attention: 64 rows/wave (halved LDS traffic), 3-deep pipeline ----------------
// grid 512 = (js 4)*(b 2)*(h 4)*(rblk 16); 4 waves x 64 rows x 128 cols
__global__ __launch_bounds__(256, 2) void k_attn1(
    const short* __restrict__ hTb, const float* __restrict__ f1,
    const float* __restrict__ Qa, const float* __restrict__ Sa,
    const unsigned* __restrict__ adjT, const unsigned* __restrict__ mx,
    short* __restrict__ part, float* __restrict__ sums){
  __shared__ short tile[3][8192];       // 48 KB: [128 hid][64 j] swizzled, 3-deep
  __shared__ float Qs[1024], Ss[1024];  // 8 KB (full js-slice)
  __shared__ unsigned abuf[3][512];     // 6 KB: [word 2][row 256] per tile
  int tid = threadIdx.x, lane = tid & 63, w = tid >> 6;   // w in 0..3
  int kgrp = lane >> 4, li = lane & 15;
  int bid = blockIdx.x;
  int js = bid >> 7, b = (bid >> 6) & 1, h = (bid >> 4) & 3, rblk = bid & 15;
  int bh = b*TH + h;
  int jbase = js * 1024;
  int r0b = rblk * 256;
  const short* hbase = hTb + ((size_t)bh*THID)*TN;
  const float* Qrow = Qa + (size_t)bh*TN + jbase;
  const float* Srow = Sa + (size_t)bh*TN + jbase;

  auto STAGE = [&](int t){
    int jg = jbase + t*64;
    int bi = t % 3;
    char* dst = (char*)tile[bi];
#pragma unroll
    for (int i = 0; i < 4; ++i){
      int s = (i*4 + w)*64 + lane;
      int row = s >> 3, c = s & 7, cs = c ^ (row & 7);
      gll16(hbase + (size_t)row*TN + jg + cs*8, dst + (i*4+w)*1024);
    }
    int w0 = jg >> 5;
#pragma unroll
    for (int k = 0; k < 2; ++k)
      gll16(adjT + (size_t)(b*NW + w0 + k)*TN + r0b + lane*4, (char*)abuf[bi] + k*1024);
  };

  // prologue: Q/S (2 ops/wave) + tiles 0,1 (6 ops/wave each)
  gll16(Qrow + w*256 + lane*4, (char*)Qs + w*1024);
  gll16(Srow + w*256 + lane*4, (char*)Ss + w*1024);
  STAGE(0); STAGE(1);

  int r0 = r0b + w*64;
  float Pv[4], Rv[4];
  int lrow[4];
  float mf = decf(mx[bh]);
#pragma unroll
  for (int rf = 0; rf < 4; ++rf){
    int row = r0 + rf*16 + li;
    lrow[rf] = w*64 + rf*16 + li;
    float f1v = f1[bh*TN + row];
    float e = f1v + mf;
    float m = e > 0.f ? e : 0.2f*e;       // leaky upper bound of all scores in row
    Pv[rf] = expf(f1v - m);
    Rv[rf] = expf(0.2f*f1v - m);
  }
  const f4 fz = {0.f,0.f,0.f,0.f};
  f4 acc[4][8];
#pragma unroll
  for (int i = 0; i < 4; ++i)
#pragma unroll
    for (int j = 0; j < 8; ++j) acc[i][j] = fz;
  f4 accs[4] = {fz, fz, fz, fz};
  s16x8 ones;
#pragma unroll
  for (int e = 0; e < 8; ++e) ones[e] = (short)0x3F80;

  for (int jt = 0; jt < 16; ++jt){
    // counted wait: keep next tile (6 ops) in flight; drain only at the end
    if (jt < 15) asm volatile("s_waitcnt vmcnt(6)" ::: "memory");
    else         asm volatile("s_waitcnt vmcnt(0)" ::: "memory");
    __builtin_amdgcn_s_barrier();
    __builtin_amdgcn_sched_barrier(0);
    if (jt < 14) STAGE(jt + 2);

    int j0 = jt*64;
    int bi = jt % 3;
    const char* tp = (const char*)tile[bi];
    const unsigned* ab = abuf[bi];
    unsigned aw0[4], aw1[4];
#pragma unroll
    for (int rf = 0; rf < 4; ++rf){
      aw0[rf] = ab[lrow[rf]];        // ks=0 word
      aw1[rf] = ab[256 + lrow[rf]];  // ks=1 word
    }
#pragma unroll
    for (int ks = 0; ks < 2; ++ks){
      int jloc = j0 + ks*32 + kgrp*8;
      float qv[8], sv[8];
      *(f4*)&qv[0] = *(const f4*)&Qs[jloc];
      *(f4*)&qv[4] = *(const f4*)&Qs[jloc+4];
      *(f4*)&sv[0] = *(const f4*)&Ss[jloc];
      *(f4*)&sv[4] = *(const f4*)&Ss[jloc+4];
      s16x8 af[4];
#pragma unroll
      for (int rf = 0; rf < 4; ++rf){
        unsigned word = ks ? aw1[rf] : aw0[rf];
        unsigned byt = (word >> (kgrp*8)) & 0xFFu;
        float P = Pv[rf], R = Rv[rf];
        u32x4 pw;
#pragma unroll
        for (int pe = 0; pe < 4; ++pe){
          float va = fmaxf(P*qv[2*pe],   R*sv[2*pe]);
          float vb = fmaxf(P*qv[2*pe+1], R*sv[2*pe+1]);
          va = (byt & (1u << (2*pe)))   ? va : 0.f;
          vb = (byt & (1u << (2*pe+1))) ? vb : 0.f;
          unsigned ua = __float_as_uint(va) + 0x8000u;  // round-half-up to bf16
          unsigned ub = __float_as_uint(vb) + 0x8000u;
          pw[pe] = __builtin_amdgcn_perm(ub, ua, 0x07060302); // pack hi16s
        }
        af[rf] = __builtin_bit_cast(s16x8, pw);
      }
#pragma unroll
      for (int rf = 0; rf < 4; ++rf)
        accs[rf] = mfma_bf16(af[rf], ones, accs[rf]);  // row sums via MFMA
#pragma unroll
      for (int cf = 0; cf < 8; ++cf){
        int col = cf*16 + li;
        int off = col*128 + (((ks*4 + kgrp) ^ (col & 7)) << 4);
        s16x8 bfr = *(const s16x8*)(tp + off);
#pragma unroll
        for (int rf = 0; rf < 4; ++rf)
          acc[rf][cf] = mfma_bf16(af[rf], bfr, acc[rf][cf]);
      }
    }
  }
  int sl = js*8 + bh;
  if (li == 0){
#pragma unroll
    for (int rf = 0; rf < 4; ++rf)
#pragma unroll
      for (int r = 0; r < 4; ++r)
        sums[(size_t)sl*TN + r0 + rf*16 + kgrp*4 + r] = accs[rf][r];
  }
#pragma unroll
  for (int rf = 0; rf < 4; ++rf)
#pragma unroll
    for (int cf = 0; cf < 8; ++cf)
#pragma unroll
      for (int r = 0; r < 4; ++r){
        int row = r0 + rf*16 + kgrp*4 + r;
        int hid = cf*16 + li;
        part[((size_t)sl*TN + row)*THID + hid] = f2bf(acc[rf][cf][r]);
      }
}

// ---------------- combine layer-1 partials (bf16, 4 slices) -> x_cat (ELU, bf16) ----------------
__global__ void k_comb1(const short* __restrict__ part, const float* __restrict__ sums,
                        short* __restrict__ xcat){
  int t = blockIdx.x*256 + threadIdx.x;   // 524,288
  int hid8 = t & 15, n = (t >> 4) & 4095, h = (t >> 16) & 3, b = t >> 18;
  int bh = b*TH + h;
  float a[8] = {0,0,0,0,0,0,0,0};
  float s = 0.f;
#pragma unroll
  for (int js = 0; js < 4; ++js){
    size_t rowoff = (size_t)(js*8 + bh)*TN + n;
    s16x8 pv = *(const s16x8*)(part + rowoff*THID + hid8*8);
#pragma unroll
    for (int e = 0; e < 8; ++e) a[e] += bf2f(pv[e]);
    s += sums[rowoff];
  }
  float inv = 1.f / s;
  s16x8 o;
#pragma unroll
  for (int e = 0; e < 8; ++e){
    float x = a[e] * inv;
    o[e] = f2bf(x > 0.f ? x : expm1f(x));
  }
  *(s16x8*)(xcat + ((size_t)(b*TN + n))*512 + h*128 + hid8*8) = o;
}

// ---------------- layer-2 projection + f1o/f2o ----------------
// grid 256, 128 thr (2 waves x 16 rows), cols = 64
__global__ __launch_bounds__(128) void k_gemm2(
    const short* __restrict__ xcat, const short* __restrict__ wo,
    const float* __restrict__ a1o, const float* __restrict__ a2o,
    short* __restrict__ h2T, float* __restrict__ f1o,
    float* __restrict__ Q2, float* __restrict__ S2, unsigned* __restrict__ mx2){
  int tid = threadIdx.x, lane = tid & 63, w = tid >> 6;
  int kgrp = lane >> 4, li = lane & 15;
  int m0 = blockIdx.x * 32;
  const f4 fz = {0.f,0.f,0.f,0.f};
  f4 acc[4] = {fz, fz, fz, fz};
  int rowA = m0 + w*16 + li;
  for (int kt = 0; kt < 16; ++kt){
    int k = kt*32 + kgrp*8;
    s16x8 a = *(const s16x8*)(xcat + (size_t)rowA*512 + k);
#pragma unroll
    for (int cf = 0; cf < 4; ++cf){
      int col = cf*16 + li;
      s16x8 bfr = *(const s16x8*)(wo + (size_t)col*512 + k);
      acc[cf] = mfma_bf16(a, bfr, acc[cf]);
    }
  }
  float p1[4] = {0,0,0,0}, p2[4] = {0,0,0,0};
#pragma unroll
  for (int cf = 0; cf < 4; ++cf){
    int o = cf*16 + li;
    float w1 = a1o[o], w2 = a2o[o];
#pragma unroll
    for (int r = 0; r < 4; ++r){
      p1[r] = fmaf(acc[cf][r], w1, p1[r]);
      p2[r] = fmaf(acc[cf][r], w2, p2[r]);
    }
  }
#pragma unroll
  for (int r = 0; r < 4; ++r){
#pragma unroll
    for (int d = 1; d < 16; d <<= 1){
      p1[r] += __shfl_xor(p1[r], d);
      p2[r] += __shfl_xor(p2[r], d);
    }
  }
#pragma unroll
  for (int cf = 0; cf < 4; ++cf)
#pragma unroll
    for (int r = 0; r < 4; ++r){
      int row = m0 + w*16 + kgrp*4 + r;
      int o = cf*16 + li;
      int b = row >> 12, n = row & 4095;
      h2T[((size_t)(b*TOUT + o))*TN + n] = f2bf(acc[cf][r]);
    }
  if (li == 0){
#pragma unroll
    for (int r = 0; r < 4; ++r){
      int row = m0 + w*16 + kgrp*4 + r;   // row == b*N + n
      f1o[row] = p1[r];
      Q2[row] = expf(p2[r]);
      S2[row] = expf(0.2f*p2[r]);
    }
  }
  float m2 = fmaxf(fmaxf(p2[0], p2[1]), fmaxf(p2[2], p2[3]));
  m2 = fmaxf(m2, __shfl_xor(m2, 16));
  m2 = fmaxf(m2, __shfl_xor(m2, 32));
  __shared__ float bm[2];
  if (lane == 0) bm[w] = m2;
  __syncthreads();
  if (tid == 0) atomicMax(&mx2[m0 >> 12], encf(fmaxf(bm[0], bm[1])));
}

// ---------------- layer-2 fused attention: 32 rows/wave, 3-deep pipeline ----------------
// grid 512 = (js 8)*(b 2)*(rblk 32); 4 waves x 32 rows x 64 cols
__global__ __launch_bounds__(256, 2) void k_attn2(
    const short* __restrict__ h2T, const float* __restrict__ f1o,
    const float* __restrict__ Q2, const float* __restrict__ S2,
    const unsigned* __restrict__ adjT, const unsigned* __restrict__ mx2,
    float* __restrict__ part, float* __restrict__ sums){
  __shared__ short tile[3][4096];     // 24 KB: [64 o][64 j] swizzled, 3-deep
  __shared__ float Qs[512], Ss[512];  // 4 KB
  __shared__ unsigned abuf[3][256];   // 3 KB: [word 2][row 128] per tile
  int tid = threadIdx.x, lane = tid & 63, w = tid >> 6;  // w in 0..3
  int kgrp = lane >> 4, li = lane & 15;
  int bid = blockIdx.x;
  int js = bid >> 6, b = (bid >> 5) & 1, rblk = bid & 31;
  int jbase = js * 512;
  int r0b = rblk * 128;
  const short* hbase = h2T + (size_t)b*TOUT*TN;
  const float* Qrow = Q2 + (size_t)b*TN + jbase;
  const float* Srow = S2 + (size_t)b*TN + jbase;

  auto STAGE = [&](int t){
    int jg = jbase + t*64;
    int bi = t % 3;
    char* dst = (char*)tile[bi];
#pragma unroll
    for (int i = 0; i < 2; ++i){
      int s = (i*4 + w)*64 + lane;
      int row = s >> 3, c = s & 7, cs = c ^ (row & 7);
      gll16(hbase + (size_t)row*TN + jg + cs*8, dst + (i*4+w)*1024);
    }
    int w0 = jg >> 5;
    gll16(adjT + (size_t)(b*NW + w0 + (lane>>5))*TN + r0b + (lane&31)*4, (char*)abuf[bi]);
  };

  if (w < 2) gll16(Qrow + w*256 + lane*4, (char*)Qs + w*1024);
  else       gll16(Srow + (w-2)*256 + lane*4, (char*)Ss + (w-2)*1024);
  STAGE(0); STAGE(1);

  int r0 = r0b + w*32;
  float Pv[2], Rv[2];
  int lrow[2];
  float mf = decf(mx2[b]);
#pragma unroll
  for (int rf = 0; rf < 2; ++rf){
    int row = r0 + rf*16 + li;
    lrow[rf] = w*32 + rf*16 + li;
    float f1v = f1o[b*TN + row];
    float e = f1v + mf;
    float m = e > 0.f ? e : 0.2f*e;
    Pv[rf] = expf(f1v - m);
    Rv[rf] = expf(0.2f*f1v - m);
  }
  const f4 fz = {0.f,0.f,0.f,0.f};
  f4 acc[2][4];
#pragma unroll
  for (int i = 0; i < 2; ++i)
#pragma unroll
    for (int j = 0; j < 4; ++j) acc[i][j] = fz;
  f4 accs[2] = {fz, fz};
  s16x8 ones;
#pragma unroll
  for (int e = 0; e < 8; ++e) ones[e] = (short)0x3F80;

  for (int jt = 0; jt < 8; ++jt){
    if (jt < 7) asm volatile("s_waitcnt vmcnt(3)" ::: "memory");
    else        asm volatile("s_waitcnt vmcnt(0)" ::: "memory");
    __builtin_amdgcn_s_barrier();
    __builtin_amdgcn_sched_barrier(0);
    if (jt < 6) STAGE(jt + 2);

    int j0 = jt*64;
    int bi = jt % 3;
    const char* tp = (const char*)tile[bi];
    const unsigned* ab = abuf[bi];
    unsigned aw0[2], aw1[2];
#pragma unroll
    for (int rf = 0; rf < 2; ++rf){
      aw0[rf] = ab[lrow[rf]];
      aw1[rf] = ab[128 + lrow[rf]];
    }
#pragma unroll
    for (int ks = 0; ks < 2; ++ks){
      int jloc = j0 + ks*32 + kgrp*8;
      float qv[8], sv[8];
      *(f4*)&qv[0] = *(const f4*)&Qs[jloc];
      *(f4*)&qv[4] = *(const f4*)&Qs[jloc+4];
      *(f4*)&sv[0] = *(const f4*)&Ss[jloc];
      *(f4*)&sv[4] = *(const f4*)&Ss[jloc+4];
      s16x8 af[2];
#pragma unroll
      for (int rf = 0; rf < 2; ++rf){
        unsigned word = ks ? aw1[rf] : aw0[rf];
        unsigned byt = (word >> (kgrp*8)) & 0xFFu;
        float P = Pv[rf], R = Rv[rf];
        u32x4 pw;
#pragma unroll
        for (int pe = 0; pe < 4; ++pe){
          float va = fmaxf(P*qv[2*pe],   R*sv[2*pe]);
          float vb = fmaxf(P*qv[2*pe+1], R*sv[2*pe+1]);
          va = (byt & (1u << (2*pe)))   ? va : 0.f;
          vb = (byt & (1u << (2*pe+1))) ? vb : 0.f;
          unsigned ua = __float_as_uint(va) + 0x8000u;
          unsigned ub = __float_as_uint(vb) + 0x8000u;
          pw[pe] = __builtin_amdgcn_perm(ub, ua, 0x07060302);
        }
        af[rf] = __builtin_bit_cast(s16x8, pw);
      }
      accs[0] = mfma_bf16(af[0], ones, accs[0]);
      accs[1] = mfma_bf16(af[1], ones, accs[1]);
#pragma unroll
      for (int cf = 0; cf < 4; ++cf){
        int col = cf*16 + li;
        int off = col*128 + (((ks*4 + kgrp) ^ (col & 7)) << 4);
        s16x8 bfr = *(const s16x8*)(tp + off);
        acc[0][cf] = mfma_bf16(af[0], bfr, acc[0][cf]);
        acc[1][cf] = mfma_bf16(af[1], bfr, acc[1][cf]);
      }
    }
  }
  int sl = js*2 + b;
  if (li == 0){
#pragma unroll
    for (int rf = 0; rf < 2; ++rf)
#pragma unroll
      for (int r = 0; r < 4; ++r)
        sums[(size_t)sl*TN + r0 + rf*16 + kgrp*4 + r] = accs[rf][r];
  }
#pragma unroll
  for (int rf = 0; rf < 2; ++rf)
#pragma unroll
    for (int cf = 0; cf < 4; ++cf)
#pragma unroll
      for (int r = 0; r < 4; ++r){
        int row = r0 + rf*16 + kgrp*4 + r;
        int o = cf*16 + li;
        part[((size_t)sl*TN + row)*TOUT + o] = acc[rf][cf][r];
      }
}

// ---------------- combine layer-2 partials -> output ----------------
__global__ void k_comb2(const float* __restrict__ part, const float* __restrict__ sums,
                        float* __restrict__ out){
  int t = blockIdx.x*256 + threadIdx.x;  // 131072
  int o4 = t & 15, n = (t >> 4) & 4095, b = t >> 16;
  f4 a = {0.f,0.f,0.f,0.f};
  float s = 0.f;
#pragma unroll
  for (int js = 0; js < 8; ++js){
    int sl = js*2 + b;
    a += ((const f4*)part)[((size_t)sl*TN + n)*16 + o4];
    s += sums[(size_t)sl*TN + n];
  }
  f4 r = a / s;
  ((f4*)out)[((size_t)(b*TN + n))*16 + o4] = r;
}

extern "C" void kernel_launch(void* const* d_in, const int* in_sizes, int n_in,
                              void* d_out, int out_size, void* d_ws, size_t ws_size,
                              hipStream_t stream) {
  (void)in_sizes; (void)n_in; (void)out_size; (void)ws_size;
  const float* x       = (const float*)d_in[0];
  const int*   adj     = (const int*)d_in[1];
  const float* W_heads = (const float*)d_in[2];
  const float* a1h     = (const float*)d_in[3];
  const float* a2h     = (const float*)d_in[4];
  const float* W_out   = (const float*)d_in[5];
  const float* a1o     = (const float*)d_in[6];
  const float* a2o     = (const float*)d_in[7];

  char* p = (char*)d_ws;
  auto alloc = [&](size_t sz){ char* r = p; p += (sz + 255) & ~(size_t)255; return r; };
  unsigned* adjT  = (unsigned*) alloc(4ull*1048576);       // 4 MB transposed bitmask, live to end
  short*    wo    = (short*)    alloc(2ull*32768);
  short*    hTb   = (short*)    alloc(2ull*4194304);       // bf16 h^T [B][H][HID][N]
  float*    f1    = (float*)    alloc(4ull*32768);
  float*    Qa    = (float*)    alloc(4ull*32768);
  float*    Sa    = (float*)    alloc(4ull*32768);
  unsigned* mx    = (unsigned*) alloc(4ull*16);            // [0..7]=layer1, [8..9]=layer2
  short*    xcat  = (short*)    alloc(2ull*4194304);
  float*    f1o   = (float*)    alloc(4ull*8192);
  float*    Q2    = (float*)    alloc(4ull*8192);
  float*    S2    = (float*)    alloc(4ull*8192);
  short*    h2T   = (short*)    alloc(2ull*524288);
  float*    sums1 = (float*)    alloc(4ull*131072);        // 32 slices x 4096
  float*    sums2 = (float*)    alloc(4ull*65536);         // 16 slices x 4096
  // union A: {xh, xl} (dead after k_gemm1) vs part1 bf16 (written by k_attn1)
  char* A = alloc(33554432ull);
  short* xh   = (short*)A;
  short* xl   = (short*)(A + 8388608);
  short* part1 = (short*)A;   // 32 sl x 4096 x 128 x 2B = 32 MB
  // union B: {wh, wl} (dead after k_gemm1) vs part2 (written by k_attn2)
  char* Bu = alloc(16777216ull);
  short* wh = (short*)Bu;
  short* wl = (short*)(Bu + 524288);
  float* part2 = (float*)Bu;  // 16 sl x 4096 x 64 x 4B = 16 MB

  k_pack <<<4096, 256, 0, stream>>>(adj, adjT, mx);
  k_split<<<4096, 256, 0, stream>>>(x, xh, xl);
  k_split<<<256, 256, 0, stream>>>(W_heads, wh, wl);
  k_cvt  <<<32, 256, 0, stream>>>(W_out, wo);
  k_gemm1<<<256, 512, 0, stream>>>(xh, xl, wh, wl, a1h, a2h, hTb, f1, Qa, Sa, mx);
  k_attn1<<<512, 256, 0, stream>>>(hTb, f1, Qa, Sa, adjT, mx, part1, sums1);
  k_comb1<<<2048, 256, 0, stream>>>(part1, sums1, xcat);
  k_gemm2<<<256, 128, 0, stream>>>(xcat, wo, a1o, a2o, h2T, f1o, Q2, S2, mx + 8);
  k_attn2<<<512, 256, 0, stream>>>(h2T, f1o, Q2, S2, adjT, mx + 8, part2, sums2);
  k_comb2<<<512, 256, 0, stream>>>(part2, sums2, (float*)d_out);
}